// Round 1
// baseline (381.244 us; speedup 1.0000x reference)
//
#include <hip/hip_runtime.h>

// out[n,c,h,w] = sum_{5x5 in-bounds taps} exp(-0.5*||xyz_nbr - xyz_ctr||^2)
//                * mask_nbr * softmax[n,c,nbr]
// OOB taps have weight forced to 0 in phase 1, so phase 2 only needs SAFE
// (clamped) addresses; clamped-position garbage is multiplied by 0.0f.
//
// R6: occupancy push. Previous layout (4px x 5ch/thread, 25.6 KB LDS,
// 120 VGPR) ran at 22% VALUBusy / 21% occupancy -> latency-bound.
// Now: block = 256 threads = 128-pixel chunk of one row.
//   Phase 1: 2 threads per pixel (half 0 -> rows 0..2, half 1 -> rows 3,4),
//            vectorized float4+scalar row loads (interior fast path).
//   Phase 2: wave = channel-group (5 ch), lane = pixel PAIR. acc/wt are
//            float2 -> half the registers of R5. LDS 12.8 KB.
// __launch_bounds__(256,6) caps VGPR at ~85 -> 6 waves/SIMD target.
// 1D grid ONLY (2D gridDim.y broke harness graph replay in R3).

#define H_DIM 64
#define W_DIM 2048
#define C_DIM 20
#define N_DIM 8
#define HW (H_DIM * W_DIM)
#define BLOCK 256
#define CHUNK 128

__global__ __launch_bounds__(BLOCK, 6) void lcx_kernel(
    const float* __restrict__ xyz,
    const float* __restrict__ sm,
    const int*  __restrict__ mask,
    float* __restrict__ out)
{
    __shared__ float w_lds[25 * CHUNK];   // [tap][pixel], 12.8 KB

    const int b  = blockIdx.x;            // 8192 blocks: 16 wchunks x 64 h x 8 n
    const int wc = b & 15;
    const int h  = (b >> 4) & (H_DIM - 1);
    const int n  = b >> 10;
    const int w0 = wc << 7;               // 128-pixel chunk base
    const int t  = threadIdx.x;

    const float* xyzn  = xyz  + n * 3 * HW;
    const int*   maskn = mask + n * HW;

    // ---------------- Phase 1: weights, 2 threads per pixel ----------------
    {
        const int px_l = t & (CHUNK - 1);
        const int half = t >> 7;              // wave-uniform
        const int px   = w0 + px_l;
        const int ctr  = h * W_DIM + px;
        const float cx = xyzn[0 * HW + ctr];
        const float cy = xyzn[1 * HW + ctr];
        const float cz = xyzn[2 * HW + ctr];
        const bool interior = (px >= 2) && (px <= W_DIM - 3);

        #pragma unroll
        for (int rr = 0; rr < 3; ++rr) {
            if (half && rr == 2) continue;    // half 1 does only rows 3,4
            const int r   = rr + (half ? 3 : 0);
            const int hi  = h + r - 2;
            const bool rok = ((unsigned)hi < (unsigned)H_DIM);
            const int hic = rok ? hi : (hi < 0 ? 0 : H_DIM - 1);
            const int rb  = hic * W_DIM;

            float w5[5];
            if (interior) {
                const int o = rb + px - 2;
                const float4 xv = *(const float4*)(xyzn + o);
                const float  xs = xyzn[o + 4];
                const float4 yv = *(const float4*)(xyzn + HW + o);
                const float  ys = xyzn[HW + o + 4];
                const float4 zv = *(const float4*)(xyzn + 2 * HW + o);
                const float  zs = xyzn[2 * HW + o + 4];
                const int4   mv = *(const int4*)(maskn + o);
                const int    ms = maskn[o + 4];
                const float nx[5] = {xv.x, xv.y, xv.z, xv.w, xs};
                const float ny[5] = {yv.x, yv.y, yv.z, yv.w, ys};
                const float nz[5] = {zv.x, zv.y, zv.z, zv.w, zs};
                const int   nm[5] = {mv.x, mv.y, mv.z, mv.w, ms};
                #pragma unroll
                for (int dj = 0; dj < 5; ++dj) {
                    const float dx = nx[dj] - cx;
                    const float dy = ny[dj] - cy;
                    const float dz = nz[dj] - cz;
                    const float d2 = fmaf(dx, dx, fmaf(dy, dy, dz * dz));
                    const bool ok = rok && (nm[dj] != 0);
                    w5[dj] = ok ? __expf(-0.5f * d2) : 0.0f;
                }
            } else {
                #pragma unroll
                for (int dj = 0; dj < 5; ++dj) {
                    const int col = px + dj - 2;
                    const bool cok = ((unsigned)col < (unsigned)W_DIM);
                    const int cc  = cok ? col : (col < 0 ? 0 : W_DIM - 1);
                    const int o   = rb + cc;
                    const float xv = xyzn[o];
                    const float yv = xyzn[HW + o];
                    const float zv = xyzn[2 * HW + o];
                    const int   mv = maskn[o];
                    const float dx = xv - cx;
                    const float dy = yv - cy;
                    const float dz = zv - cz;
                    const float d2 = fmaf(dx, dx, fmaf(dy, dy, dz * dz));
                    const bool ok = rok && cok && (mv != 0);
                    w5[dj] = ok ? __expf(-0.5f * d2) : 0.0f;
                }
            }
            #pragma unroll
            for (int dj = 0; dj < 5; ++dj)
                w_lds[(r * 5 + dj) * CHUNK + px_l] = w5[dj];
        }
    }
    __syncthreads();

    // ------------- Phase 2: 2 pixels x 5 channels per thread -------------
    const int cg = t >> 6;                // 0..3, wave-uniform channel group
    const int q  = t & 63;
    const int ql = q << 1;                // local pixel-pair base
    const int wq = w0 + ql;               // global col of pixel P0 (P1 = wq+1)

    const float* smn  = sm  + (n * C_DIM + cg * 5) * HW;
    float*       outn = out + (n * C_DIM + cg * 5) * HW;

    // window cols covered: [wq-2 .. wq+3] as float4 @ b0 + float2 @ b2
    const int  b0 = (wq >= 2) ? (wq - 2) : 0;                       // float4
    const int  b2 = (wq + 2 <= W_DIM - 2) ? (wq + 2) : (W_DIM - 2); // float2
    const bool lowedge = (wq < 2);        // only lane 0 of chunk 0

    float2 acc[5];
    #pragma unroll
    for (int c = 0; c < 5; ++c) acc[c] = make_float2(0.f, 0.f);

    #pragma unroll
    for (int r = 0; r < 5; ++r) {
        const int hi  = h + r - 2;
        const int hic = (hi < 0) ? 0 : (hi >= H_DIM ? H_DIM - 1 : hi);
        const int rbc = hic * W_DIM;      // weights are 0 for OOB rows

        float2 wt[5];                     // 5 taps x 2 pixels, ds_read_b64
        #pragma unroll
        for (int dj = 0; dj < 5; ++dj)
            wt[dj] = *(const float2*)&w_lds[(r * 5 + dj) * CHUNK + ql];

        #pragma unroll
        for (int c = 0; c < 5; ++c) {
            const float* pr = smn + c * HW + rbc;
            float4 f4 = *(const float4*)(pr + b0);
            const float2 f2 = *(const float2*)(pr + b2);
            if (lowedge) { f4.w = f4.y; f4.z = f4.x; }  // keep cols 0,1 in slots 2,3
            const float fs0 = f4.x, fs1 = f4.y, fs2 = f4.z,
                        fs3 = f4.w, fs4 = f2.x, fs5 = f2.y;
            acc[c].x = fmaf(wt[0].x, fs0, acc[c].x);
            acc[c].y = fmaf(wt[0].y, fs1, acc[c].y);
            acc[c].x = fmaf(wt[1].x, fs1, acc[c].x);
            acc[c].y = fmaf(wt[1].y, fs2, acc[c].y);
            acc[c].x = fmaf(wt[2].x, fs2, acc[c].x);
            acc[c].y = fmaf(wt[2].y, fs3, acc[c].y);
            acc[c].x = fmaf(wt[3].x, fs3, acc[c].x);
            acc[c].y = fmaf(wt[3].y, fs4, acc[c].y);
            acc[c].x = fmaf(wt[4].x, fs4, acc[c].x);
            acc[c].y = fmaf(wt[4].y, fs5, acc[c].y);
        }
    }

    const int octr = h * W_DIM + wq;
    #pragma unroll
    for (int c = 0; c < 5; ++c)
        *(float2*)(outn + c * HW + octr) = acc[c];
}

extern "C" void kernel_launch(void* const* d_in, const int* in_sizes, int n_in,
                              void* d_out, int out_size, void* d_ws, size_t ws_size,
                              hipStream_t stream)
{
    const float* xyz  = (const float*)d_in[0];
    const float* sm   = (const float*)d_in[1];
    const int*   mask = (const int*)d_in[2];
    float*       out  = (float*)d_out;

    const int grid = 16 * H_DIM * N_DIM;  // 8192 blocks, 1D ONLY

    lcx_kernel<<<grid, BLOCK, 0, stream>>>(xyz, sm, mask, out);
}

// Round 2
// 250.982 us; speedup vs baseline: 1.5190x; 1.5190x over previous
//
#include <hip/hip_runtime.h>

// out[n,c,h,w] = sum_{5x5 in-bounds taps} exp(-0.5*||xyz_nbr - xyz_ctr||^2)
//                * mask_nbr * softmax[n,c,nbr]
// OOB taps have weight forced to 0 in phase 1, so phase 2 only needs SAFE
// (clamped) addresses; clamped-position garbage is multiplied by 0.0f.
//
// R7: R6 structure, spill fix. R6's __launch_bounds__(256,6) capped VGPR at
// ~85 and the allocator spilled to 40 VGPR + scratch -> WRITE_SIZE 6.4x
// output (512 MiB), FETCH 5.8x, memory-bound on spill traffic, 276 us.
// Relax to (256,4): cap 128 VGPR (kernel needs ~80-120 naturally, no spill),
// still 16 waves/CU = ~50% occupancy vs R5's 20.7%.
//   Phase 1: 2 threads per pixel (half 0 -> rows 0..2, half 1 -> rows 3,4),
//            vectorized float4+scalar row loads (interior fast path).
//   Phase 2: wave = channel-group (5 ch), lane = pixel PAIR; float2 acc/wt,
//            LDS 12.8 KB.
// 1D grid ONLY (2D gridDim.y broke harness graph replay in R3).

#define H_DIM 64
#define W_DIM 2048
#define C_DIM 20
#define N_DIM 8
#define HW (H_DIM * W_DIM)
#define BLOCK 256
#define CHUNK 128

__global__ __launch_bounds__(BLOCK, 4) void lcx_kernel(
    const float* __restrict__ xyz,
    const float* __restrict__ sm,
    const int*  __restrict__ mask,
    float* __restrict__ out)
{
    __shared__ float w_lds[25 * CHUNK];   // [tap][pixel], 12.8 KB

    const int b  = blockIdx.x;            // 8192 blocks: 16 wchunks x 64 h x 8 n
    const int wc = b & 15;
    const int h  = (b >> 4) & (H_DIM - 1);
    const int n  = b >> 10;
    const int w0 = wc << 7;               // 128-pixel chunk base
    const int t  = threadIdx.x;

    const float* xyzn  = xyz  + n * 3 * HW;
    const int*   maskn = mask + n * HW;

    // ---------------- Phase 1: weights, 2 threads per pixel ----------------
    {
        const int px_l = t & (CHUNK - 1);
        const int half = t >> 7;              // wave-uniform
        const int px   = w0 + px_l;
        const int ctr  = h * W_DIM + px;
        const float cx = xyzn[0 * HW + ctr];
        const float cy = xyzn[1 * HW + ctr];
        const float cz = xyzn[2 * HW + ctr];
        const bool interior = (px >= 2) && (px <= W_DIM - 3);

        #pragma unroll
        for (int rr = 0; rr < 3; ++rr) {
            if (half && rr == 2) continue;    // half 1 does only rows 3,4
            const int r   = rr + (half ? 3 : 0);
            const int hi  = h + r - 2;
            const bool rok = ((unsigned)hi < (unsigned)H_DIM);
            const int hic = rok ? hi : (hi < 0 ? 0 : H_DIM - 1);
            const int rb  = hic * W_DIM;

            float w5[5];
            if (interior) {
                const int o = rb + px - 2;
                const float4 xv = *(const float4*)(xyzn + o);
                const float  xs = xyzn[o + 4];
                const float4 yv = *(const float4*)(xyzn + HW + o);
                const float  ys = xyzn[HW + o + 4];
                const float4 zv = *(const float4*)(xyzn + 2 * HW + o);
                const float  zs = xyzn[2 * HW + o + 4];
                const int4   mv = *(const int4*)(maskn + o);
                const int    ms = maskn[o + 4];
                const float nx[5] = {xv.x, xv.y, xv.z, xv.w, xs};
                const float ny[5] = {yv.x, yv.y, yv.z, yv.w, ys};
                const float nz[5] = {zv.x, zv.y, zv.z, zv.w, zs};
                const int   nm[5] = {mv.x, mv.y, mv.z, mv.w, ms};
                #pragma unroll
                for (int dj = 0; dj < 5; ++dj) {
                    const float dx = nx[dj] - cx;
                    const float dy = ny[dj] - cy;
                    const float dz = nz[dj] - cz;
                    const float d2 = fmaf(dx, dx, fmaf(dy, dy, dz * dz));
                    const bool ok = rok && (nm[dj] != 0);
                    w5[dj] = ok ? __expf(-0.5f * d2) : 0.0f;
                }
            } else {
                #pragma unroll
                for (int dj = 0; dj < 5; ++dj) {
                    const int col = px + dj - 2;
                    const bool cok = ((unsigned)col < (unsigned)W_DIM);
                    const int cc  = cok ? col : (col < 0 ? 0 : W_DIM - 1);
                    const int o   = rb + cc;
                    const float xv = xyzn[o];
                    const float yv = xyzn[HW + o];
                    const float zv = xyzn[2 * HW + o];
                    const int   mv = maskn[o];
                    const float dx = xv - cx;
                    const float dy = yv - cy;
                    const float dz = zv - cz;
                    const float d2 = fmaf(dx, dx, fmaf(dy, dy, dz * dz));
                    const bool ok = rok && cok && (mv != 0);
                    w5[dj] = ok ? __expf(-0.5f * d2) : 0.0f;
                }
            }
            #pragma unroll
            for (int dj = 0; dj < 5; ++dj)
                w_lds[(r * 5 + dj) * CHUNK + px_l] = w5[dj];
        }
    }
    __syncthreads();

    // ------------- Phase 2: 2 pixels x 5 channels per thread -------------
    const int cg = t >> 6;                // 0..3, wave-uniform channel group
    const int q  = t & 63;
    const int ql = q << 1;                // local pixel-pair base
    const int wq = w0 + ql;               // global col of pixel P0 (P1 = wq+1)

    const float* smn  = sm  + (n * C_DIM + cg * 5) * HW;
    float*       outn = out + (n * C_DIM + cg * 5) * HW;

    // window cols covered: [wq-2 .. wq+3] as float4 @ b0 + float2 @ b2
    const int  b0 = (wq >= 2) ? (wq - 2) : 0;                       // float4
    const int  b2 = (wq + 2 <= W_DIM - 2) ? (wq + 2) : (W_DIM - 2); // float2
    const bool lowedge = (wq < 2);        // only lane 0 of chunk 0

    float2 acc[5];
    #pragma unroll
    for (int c = 0; c < 5; ++c) acc[c] = make_float2(0.f, 0.f);

    #pragma unroll
    for (int r = 0; r < 5; ++r) {
        const int hi  = h + r - 2;
        const int hic = (hi < 0) ? 0 : (hi >= H_DIM ? H_DIM - 1 : hi);
        const int rbc = hic * W_DIM;      // weights are 0 for OOB rows

        float2 wt[5];                     // 5 taps x 2 pixels, ds_read_b64
        #pragma unroll
        for (int dj = 0; dj < 5; ++dj)
            wt[dj] = *(const float2*)&w_lds[(r * 5 + dj) * CHUNK + ql];

        #pragma unroll
        for (int c = 0; c < 5; ++c) {
            const float* pr = smn + c * HW + rbc;
            float4 f4 = *(const float4*)(pr + b0);
            const float2 f2 = *(const float2*)(pr + b2);
            if (lowedge) { f4.w = f4.y; f4.z = f4.x; }  // keep cols 0,1 in slots 2,3
            const float fs0 = f4.x, fs1 = f4.y, fs2 = f4.z,
                        fs3 = f4.w, fs4 = f2.x, fs5 = f2.y;
            acc[c].x = fmaf(wt[0].x, fs0, acc[c].x);
            acc[c].y = fmaf(wt[0].y, fs1, acc[c].y);
            acc[c].x = fmaf(wt[1].x, fs1, acc[c].x);
            acc[c].y = fmaf(wt[1].y, fs2, acc[c].y);
            acc[c].x = fmaf(wt[2].x, fs2, acc[c].x);
            acc[c].y = fmaf(wt[2].y, fs3, acc[c].y);
            acc[c].x = fmaf(wt[3].x, fs3, acc[c].x);
            acc[c].y = fmaf(wt[3].y, fs4, acc[c].y);
            acc[c].x = fmaf(wt[4].x, fs4, acc[c].x);
            acc[c].y = fmaf(wt[4].y, fs5, acc[c].y);
        }
    }

    const int octr = h * W_DIM + wq;
    #pragma unroll
    for (int c = 0; c < 5; ++c)
        *(float2*)(outn + c * HW + octr) = acc[c];
}

extern "C" void kernel_launch(void* const* d_in, const int* in_sizes, int n_in,
                              void* d_out, int out_size, void* d_ws, size_t ws_size,
                              hipStream_t stream)
{
    const float* xyz  = (const float*)d_in[0];
    const float* sm   = (const float*)d_in[1];
    const int*   mask = (const int*)d_in[2];
    float*       out  = (float*)d_out;

    const int grid = 16 * H_DIM * N_DIM;  // 8192 blocks, 1D ONLY

    lcx_kernel<<<grid, BLOCK, 0, stream>>>(xyz, sm, mask, out);
}

// Round 3
// 245.908 us; speedup vs baseline: 1.5504x; 1.0206x over previous
//
#include <hip/hip_runtime.h>

// out[n,c,h,w] = sum_{5x5 in-bounds taps} exp(-0.5*||xyz_nbr - xyz_ctr||^2)
//                * mask_nbr * softmax[n,c,nbr]
// OOB taps have weight forced to 0 in phase 1, so phase 2 only needs SAFE
// (clamped) addresses; clamped-slot garbage is multiplied by 0.0f.
//
// R8: revert to the proven R5 skeleton (117us: 4px x 5ch/thread, 256-px
// chunk, 25.6KB LDS, plain __launch_bounds__(256) -> 120 VGPR no spill).
// R6/R7 taught: min-waves bounds cause scratch spill (WRITE 6.4x / 1.6x
// output) and occupancy is NOT the limiter (occ 2x'd, VALUBusy flat 21%).
// Kernel is latency-bound with ~25us of real VALU work. R8 attacks latency:
//  - Phase 1 vectorized: f4+scalar row loads (40 loads/thread vs 100),
//    OOB rows write zeros with no loads. Dword-aligned dwordx4 OK (R7).
//  - Phase 2 batched: per row, issue all 15 global window loads (5ch) into
//    fs[5][8] + 5 ds_read_b128 weight reads BEFORE the 100-FMA block ->
//    15-deep MLP instead of ~3.
// 1D grid ONLY (2D gridDim.y broke harness graph replay in R3).

#define H_DIM 64
#define W_DIM 2048
#define C_DIM 20
#define N_DIM 8
#define HW (H_DIM * W_DIM)
#define BLOCK 256

__global__ __launch_bounds__(BLOCK) void lcx_kernel(
    const float* __restrict__ xyz,
    const float* __restrict__ sm,
    const int*  __restrict__ mask,
    float* __restrict__ out)
{
    __shared__ float w_lds[25 * BLOCK];   // [tap][pixel], 25.6 KB

    const int b  = blockIdx.x;            // 4096 blocks: 8 wchunks x 64 h x 8 n
    const int wc = b & 7;
    const int h  = (b >> 3) & (H_DIM - 1);
    const int n  = b >> 9;
    const int w0 = wc << 8;               // 256-pixel chunk base
    const int t  = threadIdx.x;

    const float* xyzn  = xyz  + n * 3 * HW;
    const int*   maskn = mask + n * HW;

    // -------- Phase 1: weights for pixel (h, w0+t), vectorized loads --------
    {
        const int px  = w0 + t;
        const int ctr = h * W_DIM + px;
        const float cx = xyzn[ctr];
        const float cy = xyzn[HW + ctr];
        const float cz = xyzn[2 * HW + ctr];
        const bool interior = (px >= 2) && (px <= W_DIM - 3);

        #pragma unroll
        for (int r = 0; r < 5; ++r) {
            const int hi = h + r - 2;
            float w5[5];
            if ((unsigned)hi >= (unsigned)H_DIM) {
                #pragma unroll
                for (int dj = 0; dj < 5; ++dj) w5[dj] = 0.0f;
            } else {
                const int rb = hi * W_DIM;
                if (interior) {
                    const int o = rb + px - 2;
                    const float4 xv = *(const float4*)(xyzn + o);
                    const float  xs = xyzn[o + 4];
                    const float4 yv = *(const float4*)(xyzn + HW + o);
                    const float  ys = xyzn[HW + o + 4];
                    const float4 zv = *(const float4*)(xyzn + 2 * HW + o);
                    const float  zs = xyzn[2 * HW + o + 4];
                    const int4   mv = *(const int4*)(maskn + o);
                    const int    ms = maskn[o + 4];
                    const float nx[5] = {xv.x, xv.y, xv.z, xv.w, xs};
                    const float ny[5] = {yv.x, yv.y, yv.z, yv.w, ys};
                    const float nz[5] = {zv.x, zv.y, zv.z, zv.w, zs};
                    const int   nm[5] = {mv.x, mv.y, mv.z, mv.w, ms};
                    #pragma unroll
                    for (int dj = 0; dj < 5; ++dj) {
                        const float dx = nx[dj] - cx;
                        const float dy = ny[dj] - cy;
                        const float dz = nz[dj] - cz;
                        const float d2 = fmaf(dx, dx, fmaf(dy, dy, dz * dz));
                        w5[dj] = (nm[dj] != 0) ? __expf(-0.5f * d2) : 0.0f;
                    }
                } else {
                    #pragma unroll
                    for (int dj = 0; dj < 5; ++dj) {
                        const int col = px + dj - 2;
                        const bool cok = ((unsigned)col < (unsigned)W_DIM);
                        const int cc  = cok ? col : (col < 0 ? 0 : W_DIM - 1);
                        const int o   = rb + cc;
                        const float dx = xyzn[o] - cx;
                        const float dy = xyzn[HW + o] - cy;
                        const float dz = xyzn[2 * HW + o] - cz;
                        const float d2 = fmaf(dx, dx, fmaf(dy, dy, dz * dz));
                        const bool ok = cok && (maskn[o] != 0);
                        w5[dj] = ok ? __expf(-0.5f * d2) : 0.0f;
                    }
                }
            }
            #pragma unroll
            for (int dj = 0; dj < 5; ++dj)
                w_lds[(r * 5 + dj) * BLOCK + t] = w5[dj];
        }
    }
    __syncthreads();

    // ------------- Phase 2: 4 pixels x 5 channels per thread -------------
    const int cg = t >> 6;                // 0..3, wave-uniform channel group
    const int q  = t & 63;                // pixel-quad within chunk
    const int wq = w0 + (q << 2);         // base col of this thread's 4 pixels

    const float* smn  = sm  + (n * C_DIM + cg * 5) * HW;
    float*       outn = out + (n * C_DIM + cg * 5) * HW;

    // window cols [wq-2 .. wq+5]: f2 @ b0, f4 @ b1, f2 @ b2. Slots holding
    // clamped garbage are only ever multiplied by zero weights.
    const int b0 = (wq >= 2) ? (wq - 2) : 0;                        // float2
    const int b1 = wq;                                              // float4
    const int b2 = (wq + 4 <= W_DIM - 2) ? (wq + 4) : (W_DIM - 2);  // float2

    float4 acc[5];
    #pragma unroll
    for (int c = 0; c < 5; ++c) acc[c] = make_float4(0.f, 0.f, 0.f, 0.f);

    #pragma unroll
    for (int r = 0; r < 5; ++r) {
        const int hi  = h + r - 2;
        const int hic = (hi < 0) ? 0 : (hi >= H_DIM ? H_DIM - 1 : hi);
        const int rbc = hic * W_DIM;      // weights are 0 for OOB rows

        // issue ALL 15 global window loads first -> 15-deep MLP
        float fs[5][8];
        #pragma unroll
        for (int c = 0; c < 5; ++c) {
            const float* pr = smn + c * HW + rbc;
            const float2 f0 = *(const float2*)(pr + b0);
            const float4 f1 = *(const float4*)(pr + b1);
            const float2 f2 = *(const float2*)(pr + b2);
            fs[c][0] = f0.x; fs[c][1] = f0.y;
            fs[c][2] = f1.x; fs[c][3] = f1.y;
            fs[c][4] = f1.z; fs[c][5] = f1.w;
            fs[c][6] = f2.x; fs[c][7] = f2.y;
        }

        // 5 taps x 4 pixels of weights, conflict-free b128 reads
        float4 wt[5];
        #pragma unroll
        for (int dj = 0; dj < 5; ++dj)
            wt[dj] = *(const float4*)&w_lds[(r * 5 + dj) * BLOCK + (q << 2)];

        #pragma unroll
        for (int c = 0; c < 5; ++c) {
            #pragma unroll
            for (int dj = 0; dj < 5; ++dj) {
                acc[c].x = fmaf(wt[dj].x, fs[c][0 + dj], acc[c].x);
                acc[c].y = fmaf(wt[dj].y, fs[c][1 + dj], acc[c].y);
                acc[c].z = fmaf(wt[dj].z, fs[c][2 + dj], acc[c].z);
                acc[c].w = fmaf(wt[dj].w, fs[c][3 + dj], acc[c].w);
            }
        }
    }

    const int octr = h * W_DIM + wq;
    #pragma unroll
    for (int c = 0; c < 5; ++c)
        *(float4*)(outn + c * HW + octr) = acc[c];
}

extern "C" void kernel_launch(void* const* d_in, const int* in_sizes, int n_in,
                              void* d_out, int out_size, void* d_ws, size_t ws_size,
                              hipStream_t stream)
{
    const float* xyz  = (const float*)d_in[0];
    const float* sm   = (const float*)d_in[1];
    const int*   mask = (const int*)d_in[2];
    float*       out  = (float*)d_out;

    const int grid = 8 * H_DIM * N_DIM;   // 4096 blocks, 1D ONLY

    lcx_kernel<<<grid, BLOCK, 0, stream>>>(xyz, sm, mask, out);
}